// Round 6
// baseline (154.046 us; speedup 1.0000x reference)
//
#include <hip/hip_runtime.h>

// SConv2dAvg: out[b,o,y,x] = sum_{c,kh,kw} in[b,c,2y+selh+kh,2x+selw+kw] * W[o,c,kh,kw] + bias[o]
// B=16 Cin=64 H=W=128 Cout=64 oh=ow=63 stride=2, fp32 in/out.
// Round 6: stage1 = NCHW->NHWC bf16 repack. Stage2 = 16x16x32 MFMA implicit
// GEMM with ASYNC global->LDS DMA (global_load_lds, 16B): W staged once
// (conflict-free [g][o] layout), A staged per-wave (DMA lane-scatter == MFMA
// fragment layout -> each lane ds_reads its own 16B slot; NO K-loop barriers).
// Chunk-1 DMAs issue under chunk-0 compute; explicit s_waitcnt pins pipeline.

#define B_    16
#define CIN   64
#define H_    128
#define W_    128
#define COUT  64
#define OH    63
#define OW    63
#define NPIX  (OH * OW)      // 3969
#define KTOT  (CIN * 9)      // 576

typedef short  short8  __attribute__((ext_vector_type(8)));
typedef float  float4v __attribute__((ext_vector_type(4)));

#define AS1 __attribute__((address_space(1)))
#define AS3 __attribute__((address_space(3)))

__device__ __forceinline__ void dma16(const short* g, short* l) {
    // async 16B/lane global->LDS; LDS dest = wave-uniform base + lane*16
    __builtin_amdgcn_global_load_lds((const AS1 void*)g, (AS3 void*)l, 16, 0, 0);
}

__device__ inline short f2bf(float f) {     // RN-to-even fp32 -> bf16 bits
    union { float f; unsigned u; } x; x.f = f;
    unsigned r = x.u + 0x7fffu + ((x.u >> 16) & 1u);
    return (short)(r >> 16);
}

// ---------------- stage 1a: input NCHW fp32 -> NHWC bf16 ----------------
__global__ __launch_bounds__(256)
void transpose_nhwc_bf16(const float* __restrict__ in, short* __restrict__ nhwc) {
    __shared__ float T[64 * 65];            // T[c][w], pad 65
    const int tid = threadIdx.x;
    const int w0  = blockIdx.x * 64;
    const int h   = blockIdx.y;
    const int b   = blockIdx.z;

    {   // load 64c x 64w, coalesced along w
        const int w4 = tid & 15;
        const int cl = tid >> 4;
#pragma unroll
        for (int i = 0; i < 4; ++i) {
            const int c = cl + 16 * i;
            const float4 v = *(const float4*)&in[((b * CIN + c) * H_ + h) * W_ + w0 + 4 * w4];
            T[c * 65 + 4 * w4 + 0] = v.x;
            T[c * 65 + 4 * w4 + 1] = v.y;
            T[c * 65 + 4 * w4 + 2] = v.z;
            T[c * 65 + 4 * w4 + 3] = v.w;
        }
    }
    __syncthreads();
    {   // store: 8 channels/thread as one 16B bf16 vector, coalesced along c
        const int cg = tid & 7;
        const int wl = tid >> 3;
#pragma unroll
        for (int i = 0; i < 2; ++i) {
            const int w = wl + 32 * i;
            short8 v;
#pragma unroll
            for (int t = 0; t < 8; ++t)
                v[t] = f2bf(T[(8 * cg + t) * 65 + w]);
            *(short8*)&nhwc[((b * H_ + h) * W_ + w0 + w) * CIN + 8 * cg] = v;
        }
    }
}

// ---------------- stage 1b: weight (o,c,tap) fp32 -> (o,tap,c) bf16 ----------------
__global__ __launch_bounds__(576)
void transpose_wgt_bf16(const float* __restrict__ wgt, short* __restrict__ wgt_t) {
    const int o = blockIdx.x;
    const int t = threadIdx.x;              // 0..575
    const int c = t / 9;
    const int tap = t - c * 9;
    wgt_t[o * KTOT + tap * CIN + c] = f2bf(wgt[o * KTOT + c * 9 + tap]);
}

// ---------------- stage 2: async-DMA MFMA implicit GEMM ----------------
// block: 16 pixels x 4 batches (M=64) x 32 Cout (N-split via blockIdx.z).
// 4 waves, wave wv owns m-strip 16wv..+15, does j=0,1 (o = o0+16j+ln).
// K = 2 chunks (32 ch) x 9 taps; MFMA K-step = one tap of one chunk.
#define PIXT  16
#define BT    4
#define LDO2  36

__global__ __launch_bounds__(256, 2)
void sconv2davg_mfma(const short* __restrict__ nhwc,
                     const short* __restrict__ wgt_t,
                     const float* __restrict__ bias,
                     const int* __restrict__ selh,
                     const int* __restrict__ selw,
                     float* __restrict__ out) {
    // WL[g][o2][8ch]: g = cc*36 + tap*4 + hl (72 ksegs), o2 = 0..31  (36864 B)
    __shared__ __align__(16) short WL[72 * 32 * 8];
    // AL[wv][tap][lane][8ch]: wave-private A slots                    (36864 B)
    __shared__ __align__(16) short AL[4 * 9 * 64 * 8];

    const int tid  = threadIdx.x;
    const int lane = tid & 63;
    const int wv   = tid >> 6;
    const int ln   = lane & 15;
    const int hl   = lane >> 4;             // k-quad (8ch)
    const int p0   = blockIdx.x * PIXT;
    const int b0   = blockIdx.y * BT;
    const int o0   = blockIdx.z * 32;

    // ---- per-lane A row base ----
    const int m  = 16 * wv + ln;            // 0..63
    const int pl = m >> 2;
    const int bl = m & 3;
    int p = p0 + pl;
    if (p > NPIX - 1) p = NPIX - 1;         // tail clamp; stores guarded
    const int y = p / OW;
    const int x = p - y * OW;
    const int ih0 = 2 * y + selh[p];
    const int iw0 = 2 * x + selw[p];
    const short* __restrict__ abase =
        nhwc + (((size_t)(b0 + bl) * H_ + ih0) * W_ + iw0) * CIN + hl * 8;

    // ---- issue A chunk-0 DMAs (9 per wave, wave-private slots) ----
#pragma unroll
    for (int t = 0; t < 9; ++t) {
        const int aoff = ((t / 3) * W_ + (t % 3)) * CIN;    // shorts
        dma16(abase + aoff, &AL[(wv * 9 + t) * 512]);
    }
    // ---- issue W DMAs (9 per wave; slot idx = (wv*9+i)*64+lane = g*32+o2) ----
#pragma unroll
    for (int i = 0; i < 9; ++i) {
        const int idx = (wv * 9 + i) * 64 + lane;
        const int o2  = idx & 31;
        const int g   = idx >> 5;           // 0..71
        const int cc  = g / 36;
        const int rr  = g - 36 * cc;
        const int tap = rr >> 2;
        const int hlw = rr & 3;
        const int koff = tap * CIN + cc * 32 + hlw * 8;
        dma16(wgt_t + (size_t)(o0 + o2) * KTOT + koff, &WL[(wv * 9 + i) * 512]);
    }
    asm volatile("s_waitcnt vmcnt(0)" ::: "memory");
    __syncthreads();                        // W + A-c0 landed

    // ---- read c0 A-frags to regs, then issue c1 DMAs into same slots ----
    short8 a0[9];
#pragma unroll
    for (int t = 0; t < 9; ++t)
        a0[t] = *(const short8*)&AL[((wv * 9 + t) * 64 + lane) * 8];
    asm volatile("s_waitcnt lgkmcnt(0)" ::: "memory");      // reads done, slots free
#pragma unroll
    for (int t = 0; t < 9; ++t) {
        const int aoff = ((t / 3) * W_ + (t % 3)) * CIN + 32;
        dma16(abase + aoff, &AL[(wv * 9 + t) * 512]);
    }
    asm volatile("" ::: "memory");

    float4v acc[2];
    acc[0] = (float4v){0.f, 0.f, 0.f, 0.f};
    acc[1] = (float4v){0.f, 0.f, 0.f, 0.f};

    // ---- chunk 0 compute (A from regs, B from WL; c1 DMAs in flight) ----
#pragma unroll
    for (int t = 0; t < 9; ++t) {
#pragma unroll
        for (int j = 0; j < 2; ++j) {
            const int g = t * 4 + hl;
            const short8 b = *(const short8*)&WL[(g * 32 + 16 * j + ln) * 8];
            acc[j] = __builtin_amdgcn_mfma_f32_16x16x32_bf16(a0[t], b, acc[j], 0, 0, 0);
        }
    }

    // ---- chunk 1 compute (explicit drain of c1 DMAs first) ----
    asm volatile("s_waitcnt vmcnt(0)" ::: "memory");
#pragma unroll
    for (int t = 0; t < 9; ++t) {
        const short8 a = *(const short8*)&AL[((wv * 9 + t) * 64 + lane) * 8];
#pragma unroll
        for (int j = 0; j < 2; ++j) {
            const int g = 36 + t * 4 + hl;
            const short8 b = *(const short8*)&WL[(g * 32 + 16 * j + ln) * 8];
            acc[j] = __builtin_amdgcn_mfma_f32_16x16x32_bf16(a, b, acc[j], 0, 0, 0);
        }
    }

    // ---- epilogue: C/D col=ln, row=4*hl+r -> Ot (overlay AL) -> out ----
    __syncthreads();                        // all waves done with AL
    float* Ot = (float*)AL;                 // 64 x LDO2 floats = 9216 B
#pragma unroll
    for (int j = 0; j < 2; ++j) {
        const float bv = bias[o0 + 16 * j + ln];
#pragma unroll
        for (int r = 0; r < 4; ++r)
            Ot[(16 * wv + 4 * hl + r) * LDO2 + 16 * j + ln] = acc[j][r] + bv;
    }
    __syncthreads();
    {
        const int o2   = tid & 31;
        const int b2   = (tid >> 5) & 3;
        const int half = tid >> 7;          // 0..1 -> pixels half*8..+8
        const int rowbase = ((b0 + b2) * COUT + o0 + o2) * NPIX;
#pragma unroll
        for (int q = 0; q < 8; ++q) {
            const int pp = half * 8 + q;
            const int pw = p0 + pp;
            if (pw < NPIX)
                out[rowbase + pw] = Ot[(pp * 4 + b2) * LDO2 + o2];
        }
    }
}

// ---------------- fallback (round-1 kernel) if ws too small ----------------
#define FKC   72
#define FLDA  76
__global__ __launch_bounds__(256, 4)
void sconv2davg_fallback(const float* __restrict__ in,
                         const float* __restrict__ wgt,
                         const float* __restrict__ bias,
                         const int* __restrict__ selh,
                         const int* __restrict__ selw,
                         float* __restrict__ out) {
    __shared__ float As[64 * FLDA];
    __shared__ float Ws[64 * FLDA];
    __shared__ int hb_s[4], wb_s[4];
    const int tid = threadIdx.x;
    const int p0  = blockIdx.x * 4;
    if (tid < 4) {
        int p = p0 + tid;
        if (p > NPIX - 1) p = NPIX - 1;
        int y = p / OW;
        int x = p - y * OW;
        hb_s[tid] = 2 * y + selh[p];
        wb_s[tid] = 2 * x + selw[p];
    }
    __syncthreads();
    const int tn = tid & 15, tm = tid >> 4;
    float acc[4][4];
#pragma unroll
    for (int i = 0; i < 4; ++i)
#pragma unroll
        for (int j = 0; j < 4; ++j) acc[i][j] = 0.0f;
    for (int cc = 0; cc < 8; ++cc) {
        const int c0 = cc * 8;
#pragma unroll
        for (int it = 0; it < 18; ++it) {
            int idx = tid + it * 256;
            int m = idx / FKC, rem = idx - m * FKC;
            int cl = rem / 9, r = rem - cl * 9;
            int kh = r / 3, kw = r - kh * 3;
            As[m * FLDA + rem] =
                in[((((m & 15) * CIN) + (c0 + cl)) * H_ + hb_s[m >> 4] + kh) * W_ + wb_s[m >> 4] + kw];
        }
#pragma unroll
        for (int it = 0; it < 18; ++it) {
            int idx = tid + it * 256;
            int o = idx / FKC, kk = idx - o * FKC;
            Ws[o * FLDA + kk] = wgt[o * KTOT + cc * FKC + kk];
        }
        __syncthreads();
#pragma unroll 2
        for (int k0 = 0; k0 < FKC; k0 += 4) {
            float4 a[4], w[4];
#pragma unroll
            for (int i = 0; i < 4; ++i) a[i] = *(const float4*)&As[(4 * tm + i) * FLDA + k0];
#pragma unroll
            for (int j = 0; j < 4; ++j) w[j] = *(const float4*)&Ws[(tn + 16 * j) * FLDA + k0];
#pragma unroll
            for (int i = 0; i < 4; ++i)
#pragma unroll
                for (int j = 0; j < 4; ++j) {
                    acc[i][j] += a[i].x * w[j].x; acc[i][j] += a[i].y * w[j].y;
                    acc[i][j] += a[i].z * w[j].z; acc[i][j] += a[i].w * w[j].w;
                }
        }
        __syncthreads();
    }
    const int p = p0 + (tm >> 2);
    if (p < NPIX) {
#pragma unroll
        for (int i = 0; i < 4; ++i) {
            int b = (tm & 3) * 4 + i;
#pragma unroll
            for (int j = 0; j < 4; ++j)
                out[((b * COUT) + tn + 16 * j) * NPIX + p] = acc[i][j] + bias[tn + 16 * j];
        }
    }
}

extern "C" void kernel_launch(void* const* d_in, const int* in_sizes, int n_in,
                              void* d_out, int out_size, void* d_ws, size_t ws_size,
                              hipStream_t stream) {
    const float* in   = (const float*)d_in[0];
    const float* wgt  = (const float*)d_in[1];
    const float* bias = (const float*)d_in[2];
    const int*   selh = (const int*)d_in[3];
    const int*   selw = (const int*)d_in[4];
    float* out = (float*)d_out;

    const size_t nhwc_elems = (size_t)B_ * H_ * W_ * CIN;            // 16.7M bf16
    const size_t need = (nhwc_elems + (size_t)COUT * KTOT) * 2;      // ~33.6 MB

    if (ws_size >= need) {
        short* nhwc  = (short*)d_ws;
        short* wgt_t = nhwc + nhwc_elems;
        transpose_nhwc_bf16<<<dim3(W_ / 64, H_, B_), 256, 0, stream>>>(in, nhwc);
        transpose_wgt_bf16<<<COUT, 576, 0, stream>>>(wgt, wgt_t);
        const int ptiles = (NPIX + PIXT - 1) / PIXT;                 // 249
        sconv2davg_mfma<<<dim3(ptiles, B_ / BT, 2), 256, 0, stream>>>(
            nhwc, wgt_t, bias, selh, selw, out);
    } else {
        sconv2davg_fallback<<<(NPIX + 3) / 4, 256, 0, stream>>>(
            in, wgt, bias, selh, selw, out);
    }
}

// Round 7
// 151.536 us; speedup vs baseline: 1.0166x; 1.0166x over previous
//
#include <hip/hip_runtime.h>

// SConv2dAvg: out[b,o,y,x] = sum_{c,kh,kw} in[b,c,2y+selh+kh,2x+selw+kw] * W[o,c,kh,kw] + bias[o]
// B=16 Cin=64 H=W=128 Cout=64 oh=ow=63 stride=2, fp32 in/out.
// Round 7: stage1 = NCHW->NHWC bf16 repack (unchanged). Stage2 = barrier-staged
// implicit GEMM, re-dimensioned for OCCUPANCY: 16-ch x 9-tap chunks give
// 36.9 KB LDS -> 4 blocks/CU (16 waves/CU, 2x r3-r6). mfma_f32_32x32x16_bf16,
// K-step = one tap. Pixel-minor M ordering: a wave's 16 A-rows = 16 consecutive
// x-pixels of one batch -> gather lines within a ~4 KB window.

#define B_    16
#define CIN   64
#define H_    128
#define W_    128
#define COUT  64
#define OH    63
#define OW    63
#define NPIX  (OH * OW)      // 3969
#define KTOT  (CIN * 9)      // 576

typedef short  short8   __attribute__((ext_vector_type(8)));
typedef float  floatx16 __attribute__((ext_vector_type(16)));

__device__ inline short f2bf(float f) {     // RN-to-even fp32 -> bf16 bits
    union { float f; unsigned u; } x; x.f = f;
    unsigned r = x.u + 0x7fffu + ((x.u >> 16) & 1u);
    return (short)(r >> 16);
}

// ---------------- stage 1a: input NCHW fp32 -> NHWC bf16 ----------------
__global__ __launch_bounds__(256)
void transpose_nhwc_bf16(const float* __restrict__ in, short* __restrict__ nhwc) {
    __shared__ float T[64 * 65];            // T[c][w], pad 65
    const int tid = threadIdx.x;
    const int w0  = blockIdx.x * 64;
    const int h   = blockIdx.y;
    const int b   = blockIdx.z;

    {   // load 64c x 64w, coalesced along w
        const int w4 = tid & 15;
        const int cl = tid >> 4;
#pragma unroll
        for (int i = 0; i < 4; ++i) {
            const int c = cl + 16 * i;
            const float4 v = *(const float4*)&in[((b * CIN + c) * H_ + h) * W_ + w0 + 4 * w4];
            T[c * 65 + 4 * w4 + 0] = v.x;
            T[c * 65 + 4 * w4 + 1] = v.y;
            T[c * 65 + 4 * w4 + 2] = v.z;
            T[c * 65 + 4 * w4 + 3] = v.w;
        }
    }
    __syncthreads();
    {   // store: 8 channels/thread as one 16B bf16 vector, coalesced along c
        const int cg = tid & 7;
        const int wl = tid >> 3;
#pragma unroll
        for (int i = 0; i < 2; ++i) {
            const int w = wl + 32 * i;
            short8 v;
#pragma unroll
            for (int t = 0; t < 8; ++t)
                v[t] = f2bf(T[(8 * cg + t) * 65 + w]);
            *(short8*)&nhwc[((b * H_ + h) * W_ + w0 + w) * CIN + 8 * cg] = v;
        }
    }
}

// ---------------- stage 1b: weight (o,c,tap) fp32 -> (o,tap,c) bf16 ----------------
__global__ __launch_bounds__(576)
void transpose_wgt_bf16(const float* __restrict__ wgt, short* __restrict__ wgt_t) {
    const int o = blockIdx.x;
    const int t = threadIdx.x;              // 0..575
    const int c = t / 9;
    const int tap = t - c * 9;
    wgt_t[o * KTOT + tap * CIN + c] = f2bf(wgt[o * KTOT + c * 9 + tap]);
}

// ---------------- stage 2: occupancy-tuned MFMA implicit GEMM ----------------
// block: 16 pixels x 4 batches (M=64, pixel-minor: m = bl*16 + pl) x 64 Cout.
// 4 chunks of 16 channels; K-step = one tap (32x32x16 MFMA, K=16).
// 4 waves = 2x2 grid of 32x32 tiles.
#define PIXT  16
#define BT    4
#define LDK   144   // shorts per LDS row: 9 taps * 16 ch
#define LDO   68    // epilogue staging stride (floats)

__global__ __launch_bounds__(256, 4)
void sconv2davg_mfma(const short* __restrict__ nhwc,
                     const short* __restrict__ wgt_t,
                     const float* __restrict__ bias,
                     const int* __restrict__ selh,
                     const int* __restrict__ selw,
                     float* __restrict__ out) {
    __shared__ __align__(16) short As[64 * LDK];   // 18432 B ; reused as Ot
    __shared__ __align__(16) short Ws[64 * LDK];   // 18432 B
    __shared__ int ab_s[PIXT];                     // per-pixel (ih0*W + iw0)

    const int tid = threadIdx.x;
    const int p0  = blockIdx.x * PIXT;
    const int b0  = blockIdx.y * BT;

    if (tid < PIXT) {
        int p = p0 + tid;
        if (p > NPIX - 1) p = NPIX - 1;     // tail clamp; stores guarded
        int y = p / OW;
        int x = p - y * OW;
        ab_s[tid] = (2 * y + selh[p]) * W_ + (2 * x + selw[p]);
    }
    __syncthreads();

    const int lane = tid & 63;
    const int wv   = tid >> 6;
    const int ln32 = lane & 31;             // MFMA row/col within 32
    const int h2   = lane >> 5;             // k-half (8 of 16)
    const int mw   = wv & 1;                // M-tile: rows 32*mw..+31
    const int nw   = wv >> 1;               // N-tile: cols 32*nw..+31

    const int stid = tid & 127;             // staging thread id within half

    floatx16 acc = {0.f};

#pragma unroll
    for (int cc = 0; cc < 4; ++cc) {
        const int c0 = cc * 16;
        if (cc) __syncthreads();            // compute done before restage

        // ---- stage: 2304 16B units; threads<128 -> A, >=128 -> W ----
        if (tid < 128) {
#pragma unroll
            for (int i = 0; i < 9; ++i) {
                const int u    = i * 128 + stid;     // 0..1151
                const int mm   = u / 18;             // m = bl*16 + pl
                const int r    = u - mm * 18;
                const int tap  = r >> 1;
                const int half = r & 1;
                const int kh   = tap / 3;
                const int kw   = tap - 3 * kh;
                const int bl_  = mm >> 4;
                const int pl_  = mm & 15;
                const short* src = nhwc
                    + ((size_t)(b0 + bl_) * H_ * W_ + ab_s[pl_] + kh * W_ + kw) * CIN
                    + c0 + half * 8;
                *(short8*)&As[mm * LDK + tap * 16 + half * 8] = *(const short8*)src;
            }
        } else {
#pragma unroll
            for (int i = 0; i < 9; ++i) {
                const int u    = i * 128 + stid;
                const int o    = u / 18;
                const int r    = u - o * 18;
                const int tap  = r >> 1;
                const int half = r & 1;
                *(short8*)&Ws[o * LDK + tap * 16 + half * 8] =
                    *(const short8*)&wgt_t[o * KTOT + tap * CIN + c0 + half * 8];
            }
        }
        __syncthreads();

        // ---- compute: 9 K-steps, 1 a-read + 1 b-read + 1 MFMA ----
#pragma unroll
        for (int tap = 0; tap < 9; ++tap) {
            const short8 a = *(const short8*)&As[(mw * 32 + ln32) * LDK + tap * 16 + h2 * 8];
            const short8 b = *(const short8*)&Ws[(nw * 32 + ln32) * LDK + tap * 16 + h2 * 8];
            acc = __builtin_amdgcn_mfma_f32_32x32x16_bf16(a, b, acc, 0, 0, 0);
        }
    }

    // ---- epilogue: C/D col=ln32, row=(r&3)+8*(r>>2)+4*h2 ----
    __syncthreads();
    float* Ot = (float*)As;                 // 64 x 68 floats = 17408 B <= As
    const float bv = bias[nw * 32 + ln32];
#pragma unroll
    for (int r = 0; r < 16; ++r) {
        const int row = (r & 3) + 8 * (r >> 2) + 4 * h2;
        Ot[(mw * 32 + row) * LDO + nw * 32 + ln32] = acc[r] + bv;
    }
    __syncthreads();
    {
        const int o  = tid & 63;
        const int b2 = tid >> 6;            // batch within block (pixel-minor m)
        const int rowbase = ((b0 + b2) * COUT + o) * NPIX;
#pragma unroll
        for (int pp = 0; pp < PIXT; ++pp) {
            const int pw = p0 + pp;
            if (pw < NPIX)
                out[rowbase + pw] = Ot[(b2 * 16 + pp) * LDO + o];
        }
    }
}

// ---------------- fallback (round-1 kernel) if ws too small ----------------
#define FKC   72
#define FLDA  76
__global__ __launch_bounds__(256, 4)
void sconv2davg_fallback(const float* __restrict__ in,
                         const float* __restrict__ wgt,
                         const float* __restrict__ bias,
                         const int* __restrict__ selh,
                         const int* __restrict__ selw,
                         float* __restrict__ out) {
    __shared__ float As[64 * FLDA];
    __shared__ float Ws[64 * FLDA];
    __shared__ int hb_s[4], wb_s[4];
    const int tid = threadIdx.x;
    const int p0  = blockIdx.x * 4;
    if (tid < 4) {
        int p = p0 + tid;
        if (p > NPIX - 1) p = NPIX - 1;
        int y = p / OW;
        int x = p - y * OW;
        hb_s[tid] = 2 * y + selh[p];
        wb_s[tid] = 2 * x + selw[p];
    }
    __syncthreads();
    const int tn = tid & 15, tm = tid >> 4;
    float acc[4][4];
#pragma unroll
    for (int i = 0; i < 4; ++i)
#pragma unroll
        for (int j = 0; j < 4; ++j) acc[i][j] = 0.0f;
    for (int cc = 0; cc < 8; ++cc) {
        const int c0 = cc * 8;
#pragma unroll
        for (int it = 0; it < 18; ++it) {
            int idx = tid + it * 256;
            int m = idx / FKC, rem = idx - m * FKC;
            int cl = rem / 9, r = rem - cl * 9;
            int kh = r / 3, kw = r - kh * 3;
            As[m * FLDA + rem] =
                in[((((m & 15) * CIN) + (c0 + cl)) * H_ + hb_s[m >> 4] + kh) * W_ + wb_s[m >> 4] + kw];
        }
#pragma unroll
        for (int it = 0; it < 18; ++it) {
            int idx = tid + it * 256;
            int o = idx / FKC, kk = idx - o * FKC;
            Ws[o * FLDA + kk] = wgt[o * KTOT + cc * FKC + kk];
        }
        __syncthreads();
#pragma unroll 2
        for (int k0 = 0; k0 < FKC; k0 += 4) {
            float4 a[4], w[4];
#pragma unroll
            for (int i = 0; i < 4; ++i) a[i] = *(const float4*)&As[(4 * tm + i) * FLDA + k0];
#pragma unroll
            for (int j = 0; j < 4; ++j) w[j] = *(const float4*)&Ws[(tn + 16 * j) * FLDA + k0];
#pragma unroll
            for (int i = 0; i < 4; ++i)
#pragma unroll
                for (int j = 0; j < 4; ++j) {
                    acc[i][j] += a[i].x * w[j].x; acc[i][j] += a[i].y * w[j].y;
                    acc[i][j] += a[i].z * w[j].z; acc[i][j] += a[i].w * w[j].w;
                }
        }
        __syncthreads();
    }
    const int p = p0 + (tm >> 2);
    if (p < NPIX) {
#pragma unroll
        for (int i = 0; i < 4; ++i) {
            int b = (tm & 3) * 4 + i;
#pragma unroll
            for (int j = 0; j < 4; ++j)
                out[((b * COUT) + tn + 16 * j) * NPIX + p] = acc[i][j] + bias[tn + 16 * j];
        }
    }
}

extern "C" void kernel_launch(void* const* d_in, const int* in_sizes, int n_in,
                              void* d_out, int out_size, void* d_ws, size_t ws_size,
                              hipStream_t stream) {
    const float* in   = (const float*)d_in[0];
    const float* wgt  = (const float*)d_in[1];
    const float* bias = (const float*)d_in[2];
    const int*   selh = (const int*)d_in[3];
    const int*   selw = (const int*)d_in[4];
    float* out = (float*)d_out;

    const size_t nhwc_elems = (size_t)B_ * H_ * W_ * CIN;            // 16.7M bf16
    const size_t need = (nhwc_elems + (size_t)COUT * KTOT) * 2;      // ~33.6 MB

    if (ws_size >= need) {
        short* nhwc  = (short*)d_ws;
        short* wgt_t = nhwc + nhwc_elems;
        transpose_nhwc_bf16<<<dim3(W_ / 64, H_, B_), 256, 0, stream>>>(in, nhwc);
        transpose_wgt_bf16<<<COUT, 576, 0, stream>>>(wgt, wgt_t);
        const int ptiles = (NPIX + PIXT - 1) / PIXT;                 // 249
        sconv2davg_mfma<<<dim3(ptiles, B_ / BT), 256, 0, stream>>>(
            nhwc, wgt_t, bias, selh, selw, out);
    } else {
        sconv2davg_fallback<<<(NPIX + 3) / 4, 256, 0, stream>>>(
            in, wgt, bias, selh, selw, out);
    }
}

// Round 8
// 146.913 us; speedup vs baseline: 1.0485x; 1.0315x over previous
//
#include <hip/hip_runtime.h>

// SConv2dAvg: out[b,o,y,x] = sum_{c,kh,kw} in[b,c,2y+selh+kh,2x+selw+kw] * W[o,c,kh,kw] + bias[o]
// B=16 Cin=64 H=W=128 Cout=64 oh=ow=63 stride=2, fp32 in/out.
// Round 8: r5 skeleton + pinned pipelining.
//  - stage1a: NCHW -> NHWC bf16.
//  - stage1b: weights -> DMA-ready unit layout wgt2[(tap*8 + (c>>3))*64 + o][c&7].
//  - stage2: W staged once via global_load_lds (coalesced + conflict-free,
//    0 VGPR); A = 36x16B direct global->reg preload PINNED by
//    sched_barrier(0) so the compiler cannot sink it (r5's failure mode);
//    single vmcnt(0) + one barrier; 36 MFMA (32x32x16) from regs+LDS.

#define B_    16
#define CIN   64
#define H_    128
#define W_    128
#define COUT  64
#define OH    63
#define OW    63
#define NPIX  (OH * OW)      // 3969
#define KTOT  (CIN * 9)      // 576

typedef short  short8   __attribute__((ext_vector_type(8)));
typedef float  floatx16 __attribute__((ext_vector_type(16)));

#define AS1 __attribute__((address_space(1)))
#define AS3 __attribute__((address_space(3)))

__device__ __forceinline__ void dma16(const short* g, short* l) {
    // async 16B/lane global->LDS; LDS dest = wave-uniform base + lane*16
    __builtin_amdgcn_global_load_lds((const AS1 void*)g, (AS3 void*)l, 16, 0, 0);
}

__device__ inline short f2bf(float f) {     // RN-to-even fp32 -> bf16 bits
    union { float f; unsigned u; } x; x.f = f;
    unsigned r = x.u + 0x7fffu + ((x.u >> 16) & 1u);
    return (short)(r >> 16);
}

// ---------------- stage 1a: input NCHW fp32 -> NHWC bf16 ----------------
__global__ __launch_bounds__(256)
void transpose_nhwc_bf16(const float* __restrict__ in, short* __restrict__ nhwc) {
    __shared__ float T[64 * 65];            // T[c][w], pad 65
    const int tid = threadIdx.x;
    const int w0  = blockIdx.x * 64;
    const int h   = blockIdx.y;
    const int b   = blockIdx.z;

    {   // load 64c x 64w, coalesced along w
        const int w4 = tid & 15;
        const int cl = tid >> 4;
#pragma unroll
        for (int i = 0; i < 4; ++i) {
            const int c = cl + 16 * i;
            const float4 v = *(const float4*)&in[((b * CIN + c) * H_ + h) * W_ + w0 + 4 * w4];
            T[c * 65 + 4 * w4 + 0] = v.x;
            T[c * 65 + 4 * w4 + 1] = v.y;
            T[c * 65 + 4 * w4 + 2] = v.z;
            T[c * 65 + 4 * w4 + 3] = v.w;
        }
    }
    __syncthreads();
    {   // store: 8 channels/thread as one 16B bf16 vector, coalesced along c
        const int cg = tid & 7;
        const int wl = tid >> 3;
#pragma unroll
        for (int i = 0; i < 2; ++i) {
            const int w = wl + 32 * i;
            short8 v;
#pragma unroll
            for (int t = 0; t < 8; ++t)
                v[t] = f2bf(T[(8 * cg + t) * 65 + w]);
            *(short8*)&nhwc[((b * H_ + h) * W_ + w0 + w) * CIN + 8 * cg] = v;
        }
    }
}

// -------- stage 1b: weight (o,c,tap) fp32 -> DMA-ready unit layout bf16 -----
// GEMM k-order: k = tap*64 + c.  16B unit g = (tap*8 + (c>>3)); wgt2 holds
// units g-major over o: wgt2[(g*64 + o)*8 + (c&7)].
__global__ __launch_bounds__(576)
void transpose_wgt_bf16(const float* __restrict__ wgt, short* __restrict__ wgt2) {
    const int o = blockIdx.x;
    const int t = threadIdx.x;              // 0..575
    const int c = t / 9;
    const int tap = t - c * 9;
    const int g = tap * 8 + (c >> 3);
    wgt2[(g * 64 + o) * 8 + (c & 7)] = f2bf(wgt[o * KTOT + c * 9 + tap]);
}

// ---------------- stage 2: pinned-pipeline MFMA implicit GEMM ----------------
// block: 16 pixels x 4 batches (M=64, pixel-minor m = bl*16 + pl) x 64 Cout.
// 4 waves = 2x2 grid of 32x32 tiles; K = 576 = 36 steps of 16 (tap-major).
#define PIXT  16
#define BT    4
#define LDO   68    // epilogue staging stride (floats)

__global__ __launch_bounds__(256, 2)
void sconv2davg_mfma(const short* __restrict__ nhwc,
                     const short* __restrict__ wgt2,
                     const float* __restrict__ bias,
                     const int* __restrict__ selh,
                     const int* __restrict__ selw,
                     float* __restrict__ out) {
    __shared__ __align__(16) short WL[72 * 64 * 8];   // 73728 B; reused as Ot

    const int tid  = threadIdx.x;
    const int lane = tid & 63;
    const int wv   = tid >> 6;
    const int ln32 = lane & 31;             // MFMA row/col within 32
    const int h2   = lane >> 5;             // k-half (8 of 16)
    const int mw   = wv & 1;                // M-tile: rows 32*mw..+31
    const int nw   = wv >> 1;               // N-tile: cols 32*nw..+31
    const int p0   = blockIdx.x * PIXT;
    const int b0   = blockIdx.y * BT;

    // ---- W staging: 18 DMA per wave; unit u = i*256 + wv*64 + lane ----
#pragma unroll
    for (int i = 0; i < 18; ++i) {
        const int ub = i * 256 + wv * 64;   // wave-uniform unit base
        dma16(wgt2 + ((size_t)ub + lane) * 8, &WL[ub * 8]);
    }

    // ---- per-lane A row (pixel-minor: m = bl*16 + pl) ----
    const int m  = mw * 32 + ln32;
    const int bl = m >> 4;
    const int pl = m & 15;
    int p = p0 + pl;
    if (p > NPIX - 1) p = NPIX - 1;         // tail clamp; stores guarded
    const int y = p / OW;
    const int x = p - y * OW;
    const int ih0 = 2 * y + selh[p];
    const int iw0 = 2 * x + selw[p];
    const short* __restrict__ arow =
        nhwc + (((size_t)(b0 + bl) * H_ + ih0) * W_ + iw0) * CIN + h2 * 8;

    // ---- A preload: 36 x 16B, PINNED (do not let the scheduler sink) ----
    short8 areg[36];
#pragma unroll
    for (int s = 0; s < 36; ++s) {
        const int tap = s >> 2, q = s & 3;
        const int kh = tap / 3, kw = tap - 3 * (tap / 3);
        areg[s] = *(const short8*)&arow[(kh * W_ + kw) * CIN + q * 16];
    }
    __builtin_amdgcn_sched_barrier(0);      // hard fence: loads stay above
    asm volatile("s_waitcnt vmcnt(0)" ::: "memory");
    __syncthreads();                        // W landed in LDS

    // ---- K loop: 36 steps, 1 ds_read_b128 + 1 MFMA, dual acc chains ----
    floatx16 acc0 = {0.f}, acc1 = {0.f};
#pragma unroll
    for (int s = 0; s < 36; s += 2) {
        const short8 b0f = *(const short8*)
            &WL[(((s + 0) * 2 + h2) * 64 + nw * 32 + ln32) * 8];
        acc0 = __builtin_amdgcn_mfma_f32_32x32x16_bf16(areg[s + 0], b0f, acc0, 0, 0, 0);
        const short8 b1f = *(const short8*)
            &WL[(((s + 1) * 2 + h2) * 64 + nw * 32 + ln32) * 8];
        acc1 = __builtin_amdgcn_mfma_f32_32x32x16_bf16(areg[s + 1], b1f, acc1, 0, 0, 0);
    }

    __syncthreads();                        // all WL reads done; reuse as Ot

    // ---- epilogue: C/D col=ln32, row=(r&3)+8*(r>>2)+4*h2 ----
    float* Ot = (float*)WL;                 // 64 x 68 floats = 17408 B
    const float bv = bias[nw * 32 + ln32];
#pragma unroll
    for (int r = 0; r < 16; ++r) {
        const int row = (r & 3) + 8 * (r >> 2) + 4 * h2;
        Ot[(mw * 32 + row) * LDO + nw * 32 + ln32] = acc0[r] + acc1[r] + bv;
    }
    __syncthreads();
    {
        const int o  = tid & 63;
        const int b2 = tid >> 6;            // block-local batch (pixel-minor m)
        const int rowbase = ((b0 + b2) * COUT + o) * NPIX;
#pragma unroll
        for (int pp = 0; pp < PIXT; ++pp) {
            const int pw = p0 + pp;
            if (pw < NPIX)
                out[rowbase + pw] = Ot[(b2 * 16 + pp) * LDO + o];
        }
    }
}

// ---------------- fallback (round-1 kernel) if ws too small ----------------
#define FKC   72
#define FLDA  76
__global__ __launch_bounds__(256, 4)
void sconv2davg_fallback(const float* __restrict__ in,
                         const float* __restrict__ wgt,
                         const float* __restrict__ bias,
                         const int* __restrict__ selh,
                         const int* __restrict__ selw,
                         float* __restrict__ out) {
    __shared__ float As[64 * FLDA];
    __shared__ float Ws[64 * FLDA];
    __shared__ int hb_s[4], wb_s[4];
    const int tid = threadIdx.x;
    const int p0  = blockIdx.x * 4;
    if (tid < 4) {
        int p = p0 + tid;
        if (p > NPIX - 1) p = NPIX - 1;
        int y = p / OW;
        int x = p - y * OW;
        hb_s[tid] = 2 * y + selh[p];
        wb_s[tid] = 2 * x + selw[p];
    }
    __syncthreads();
    const int tn = tid & 15, tm = tid >> 4;
    float acc[4][4];
#pragma unroll
    for (int i = 0; i < 4; ++i)
#pragma unroll
        for (int j = 0; j < 4; ++j) acc[i][j] = 0.0f;
    for (int cc = 0; cc < 8; ++cc) {
        const int c0 = cc * 8;
#pragma unroll
        for (int it = 0; it < 18; ++it) {
            int idx = tid + it * 256;
            int m = idx / FKC, rem = idx - m * FKC;
            int cl = rem / 9, r = rem - cl * 9;
            int kh = r / 3, kw = r - kh * 3;
            As[m * FLDA + rem] =
                in[((((m & 15) * CIN) + (c0 + cl)) * H_ + hb_s[m >> 4] + kh) * W_ + wb_s[m >> 4] + kw];
        }
#pragma unroll
        for (int it = 0; it < 18; ++it) {
            int idx = tid + it * 256;
            int o = idx / FKC, kk = idx - o * FKC;
            Ws[o * FLDA + kk] = wgt[o * KTOT + cc * FKC + kk];
        }
        __syncthreads();
#pragma unroll 2
        for (int k0 = 0; k0 < FKC; k0 += 4) {
            float4 a[4], w[4];
#pragma unroll
            for (int i = 0; i < 4; ++i) a[i] = *(const float4*)&As[(4 * tm + i) * FLDA + k0];
#pragma unroll
            for (int j = 0; j < 4; ++j) w[j] = *(const float4*)&Ws[(tn + 16 * j) * FLDA + k0];
#pragma unroll
            for (int i = 0; i < 4; ++i)
#pragma unroll
                for (int j = 0; j < 4; ++j) {
                    acc[i][j] += a[i].x * w[j].x; acc[i][j] += a[i].y * w[j].y;
                    acc[i][j] += a[i].z * w[j].z; acc[i][j] += a[i].w * w[j].w;
                }
        }
        __syncthreads();
    }
    const int p = p0 + (tm >> 2);
    if (p < NPIX) {
#pragma unroll
        for (int i = 0; i < 4; ++i) {
            int b = (tm & 3) * 4 + i;
#pragma unroll
            for (int j = 0; j < 4; ++j)
                out[((b * COUT) + tn + 16 * j) * NPIX + p] = acc[i][j] + bias[tn + 16 * j];
        }
    }
}

extern "C" void kernel_launch(void* const* d_in, const int* in_sizes, int n_in,
                              void* d_out, int out_size, void* d_ws, size_t ws_size,
                              hipStream_t stream) {
    const float* in   = (const float*)d_in[0];
    const float* wgt  = (const float*)d_in[1];
    const float* bias = (const float*)d_in[2];
    const int*   selh = (const int*)d_in[3];
    const int*   selw = (const int*)d_in[4];
    float* out = (float*)d_out;

    const size_t nhwc_elems = (size_t)B_ * H_ * W_ * CIN;            // 16.7M bf16
    const size_t need = (nhwc_elems + (size_t)COUT * KTOT) * 2;      // ~33.6 MB

    if (ws_size >= need) {
        short* nhwc = (short*)d_ws;
        short* wgt2 = nhwc + nhwc_elems;
        transpose_nhwc_bf16<<<dim3(W_ / 64, H_, B_), 256, 0, stream>>>(in, nhwc);
        transpose_wgt_bf16<<<COUT, 576, 0, stream>>>(wgt, wgt2);
        const int ptiles = (NPIX + PIXT - 1) / PIXT;                 // 249
        sconv2davg_mfma<<<dim3(ptiles, B_ / BT), 256, 0, stream>>>(
            nhwc, wgt2, bias, selh, selw, out);
    } else {
        sconv2davg_fallback<<<(NPIX + 3) / 4, 256, 0, stream>>>(
            in, wgt, bias, selh, selw, out);
    }
}